// Round 1
// baseline (1086.256 us; speedup 1.0000x reference)
//
#include <hip/hip_runtime.h>

#define SB 2
#define HH 8
#define SS 2048
#define DM 512
#define HD 64
#define NR 513
#define SCALE 0.125f

static __device__ __forceinline__ unsigned short f2bf(float x) {
  unsigned int u = __float_as_uint(x);
  unsigned int r = (u + 0x7FFFu + ((u >> 16) & 1u)) >> 16;
  return (unsigned short)r;
}
static __device__ __forceinline__ float bf2f(unsigned short s) {
  return __uint_as_float(((unsigned int)s) << 16);
}

// ---------------- generic fp32 GEMM: C[M][N] = A[M][K] @ B[K][N] (+bias) ---
__global__ __launch_bounds__(256) void gemm_f32(const float* __restrict__ A,
                                                const float* __restrict__ Bm,
                                                const float* __restrict__ bias,
                                                float* __restrict__ C,
                                                int M, int N, int K) {
  __shared__ float As[16][68];   // [k][m], padded
  __shared__ float Bs[16][64];   // [k][n]
  const int t = threadIdx.x;
  const int nb = N >> 6;
  const int bm = blockIdx.x / nb, bn = blockIdx.x % nb;
  const int m0 = bm << 6, n0 = bn << 6;
  const int ty = t >> 4, tx = t & 15;
  const int mr = ty << 2, nc = tx << 2;
  const int am = t >> 2, akq = t & 3;
  const int bk = t >> 4, bnq = t & 15;
  float acc[4][4] = {};
  for (int k0 = 0; k0 < K; k0 += 16) {
    const float4 av = *(const float4*)&A[(size_t)(m0 + am) * K + k0 + (akq << 2)];
    const float4 bv = *(const float4*)&Bm[(size_t)(k0 + bk) * N + n0 + (bnq << 2)];
    __syncthreads();
    As[(akq << 2) + 0][am] = av.x;
    As[(akq << 2) + 1][am] = av.y;
    As[(akq << 2) + 2][am] = av.z;
    As[(akq << 2) + 3][am] = av.w;
    *(float4*)&Bs[bk][bnq << 2] = bv;
    __syncthreads();
#pragma unroll
    for (int kk = 0; kk < 16; ++kk) {
      float a[4], b[4];
      *(float4*)a = *(const float4*)&As[kk][mr];
      *(float4*)b = *(const float4*)&Bs[kk][nc];
#pragma unroll
      for (int i = 0; i < 4; ++i)
#pragma unroll
        for (int j = 0; j < 4; ++j) acc[i][j] += a[i] * b[j];
    }
  }
#pragma unroll
  for (int i = 0; i < 4; ++i) {
    float4 v = make_float4(acc[i][0], acc[i][1], acc[i][2], acc[i][3]);
    if (bias) {
      v.x += bias[n0 + nc + 0];
      v.y += bias[n0 + nc + 1];
      v.z += bias[n0 + nc + 2];
      v.w += bias[n0 + nc + 3];
    }
    *(float4*)&C[(size_t)(m0 + mr + i) * N + n0 + nc] = v;
  }
}

// -------- logits: alpha = (q.k + q.Ek[rpr])/8, write raw logits + row m,Z ---
// grid: (B*H) * 128 blocks, each block = 16 rows, loops all 2048 cols.
__global__ __launch_bounds__(256) void attn_logits(const float* __restrict__ Q,
                                                   const float* __restrict__ Kp,
                                                   const float* __restrict__ Ek,
                                                   float* __restrict__ attn,
                                                   float* __restrict__ m_out,
                                                   float* __restrict__ z_out) {
  __shared__ float ks[64][68];     // [d][j] transposed K tile (or Ek tile)
  __shared__ float qek[16][NR];    // per-row relative logit term
  __shared__ float red[16][17];
  __shared__ float mnew[16];
  const int t = threadIdx.x;
  const int itile = blockIdx.x & 127;
  const int bh = blockIdx.x >> 7;
  const int b = bh >> 3, h = bh & 7;
  const int i0 = itile << 4;
  const int ti = t >> 4, tj = t & 15;
  const int iglob = i0 + ti;

  // q row in registers (64 floats, all indices compile-time via full unroll)
  float qr[64];
  {
    const float* qrow = Q + ((size_t)b * SS + iglob) * DM + h * HD;
#pragma unroll
    for (int d4 = 0; d4 < 16; ++d4) {
      float4 v = *(const float4*)&qrow[d4 << 2];
      qr[(d4 << 2) + 0] = v.x;
      qr[(d4 << 2) + 1] = v.y;
      qr[(d4 << 2) + 2] = v.z;
      qr[(d4 << 2) + 3] = v.w;
    }
  }

  // qek[i][r] = q_i . Ek[r], chunks of 64 r staged (transposed) through ks
  for (int rc = 0; rc < 512; rc += 64) {
#pragma unroll
    for (int u = 0; u < 4; ++u) {
      const int l = t + (u << 8);
      const int rr = l >> 4, dq = l & 15;
      float4 v = *(const float4*)&Ek[(size_t)(rc + rr) * HD + (dq << 2)];
      ks[(dq << 2) + 0][rr] = v.x;
      ks[(dq << 2) + 1][rr] = v.y;
      ks[(dq << 2) + 2][rr] = v.z;
      ks[(dq << 2) + 3][rr] = v.w;
    }
    __syncthreads();
    float a0 = 0.f, a1 = 0.f, a2 = 0.f, a3 = 0.f;
    const int r0 = tj << 2;
#pragma unroll
    for (int d = 0; d < 64; ++d) {
      const float4 kv = *(const float4*)&ks[d][r0];
      const float q = qr[d];
      a0 += q * kv.x; a1 += q * kv.y; a2 += q * kv.z; a3 += q * kv.w;
    }
    qek[ti][rc + r0 + 0] = a0;
    qek[ti][rc + r0 + 1] = a1;
    qek[ti][rc + r0 + 2] = a2;
    qek[ti][rc + r0 + 3] = a3;
    __syncthreads();
  }
  if (tj == 0) {  // r = 512
    float a = 0.f;
#pragma unroll
    for (int d = 0; d < 64; ++d) a += qr[d] * Ek[512 * HD + d];
    qek[ti][512] = a;
  }
  __syncthreads();

  float mrun = -INFINITY, zrun = 0.f;  // live in leader threads (tj==0)
  float* attn_row = attn + ((size_t)bh * SS + iglob) * SS;

  for (int jt = 0; jt < 32; ++jt) {
    const int j0t = jt << 6;
    // stage K tile transposed: ks[d][j]
#pragma unroll
    for (int u = 0; u < 4; ++u) {
      const int l = t + (u << 8);
      const int jj = l >> 4, dq = l & 15;
      float4 v = *(const float4*)&Kp[((size_t)b * SS + j0t + jj) * DM + h * HD + (dq << 2)];
      ks[(dq << 2) + 0][jj] = v.x;
      ks[(dq << 2) + 1][jj] = v.y;
      ks[(dq << 2) + 2][jj] = v.z;
      ks[(dq << 2) + 3][jj] = v.w;
    }
    __syncthreads();
    float acc[4] = {};
    const int j0 = tj << 2;
#pragma unroll
    for (int d = 0; d < 64; ++d) {
      const float4 kv = *(const float4*)&ks[d][j0];
      const float q = qr[d];
      acc[0] += q * kv.x; acc[1] += q * kv.y; acc[2] += q * kv.z; acc[3] += q * kv.w;
    }
    float al[4];
#pragma unroll
    for (int u = 0; u < 4; ++u) {
      const int j = j0t + j0 + u;
      int off = j - iglob;
      off = off < -256 ? -256 : (off > 256 ? 256 : off);
      al[u] = (acc[u] + qek[ti][off + 256]) * SCALE;
    }
    *(float4*)&attn_row[j0t + j0] = make_float4(al[0], al[1], al[2], al[3]);
    // online row stats
    float ml = fmaxf(fmaxf(al[0], al[1]), fmaxf(al[2], al[3]));
    red[ti][tj] = ml;
    __syncthreads();
    if (tj == 0) {
      float m = mrun;
#pragma unroll
      for (int x = 0; x < 16; ++x) m = fmaxf(m, red[ti][x]);
      mnew[ti] = m;
    }
    __syncthreads();
    const float mm = mnew[ti];
    float zl = __expf(al[0] - mm) + __expf(al[1] - mm) + __expf(al[2] - mm) + __expf(al[3] - mm);
    red[ti][tj] = zl;
    __syncthreads();
    if (tj == 0) {
      float z = 0.f;
#pragma unroll
      for (int x = 0; x < 16; ++x) z += red[ti][x];
      zrun = zrun * __expf(mrun - mm) + z;
      mrun = mm;
    }
    __syncthreads();
  }
  if (tj == 0) {
    m_out[(size_t)bh * SS + iglob] = mrun;
    z_out[(size_t)bh * SS + iglob] = zrun;
  }
}

// -------- PV: normalize weights (write back), scores = w@V + w_rel@Ev ------
// grid: (B*H) * 64 blocks, each block = 32 rows.
__global__ __launch_bounds__(256) void attn_pv(const float* __restrict__ V,
                                               const float* __restrict__ Ev,
                                               const float* __restrict__ m_in,
                                               const float* __restrict__ z_in,
                                               float* __restrict__ attn,
                                               float* __restrict__ concat) {
  __shared__ float vs[64][68];              // V tile or Ev chunk
  __shared__ unsigned short wrel[32][NR];   // per-row relative weight bins (bf16)
  __shared__ float wsm[32][68];             // current weight tile
  const int t = threadIdx.x;
  const int itile = blockIdx.x & 63;
  const int bh = blockIdx.x >> 6;
  const int b = bh >> 3, h = bh & 7;
  const int i0 = itile << 5;
  const int ti = t >> 3, dq = t & 7;
  const int d0 = dq << 3;
  const int iglob = i0 + ti;
  const float mi = m_in[(size_t)bh * SS + iglob];
  const float zi = 1.f / z_in[(size_t)bh * SS + iglob];

  unsigned short* wrelf = &wrel[0][0];
  for (int x = t; x < 32 * NR; x += 256) wrelf[x] = 0;
  __syncthreads();

  float acc[8] = {};
  float lacc = 0.f, hacc = 0.f;  // clamped bins r=0 / r=512
  float* attn_row = attn + ((size_t)bh * SS + iglob) * SS;

  for (int jt = 0; jt < 32; ++jt) {
    const int j0t = jt << 6;
#pragma unroll
    for (int u = 0; u < 4; ++u) {
      const int l = t + (u << 8);
      const int jj = l >> 4, dv = (l & 15) << 2;
      *(float4*)&vs[jj][dv] =
          *(const float4*)&V[((size_t)b * SS + j0t + jj) * DM + h * HD + dv];
    }
    const float4 a1 = *(const float4*)&attn_row[j0t + d0];
    const float4 a2 = *(const float4*)&attn_row[j0t + d0 + 4];
    float w[8];
    w[0] = __expf(a1.x - mi) * zi; w[1] = __expf(a1.y - mi) * zi;
    w[2] = __expf(a1.z - mi) * zi; w[3] = __expf(a1.w - mi) * zi;
    w[4] = __expf(a2.x - mi) * zi; w[5] = __expf(a2.y - mi) * zi;
    w[6] = __expf(a2.z - mi) * zi; w[7] = __expf(a2.w - mi) * zi;
    *(float4*)&attn_row[j0t + d0] = make_float4(w[0], w[1], w[2], w[3]);
    *(float4*)&attn_row[j0t + d0 + 4] = make_float4(w[4], w[5], w[6], w[7]);
    *(float4*)&wsm[ti][d0] = make_float4(w[0], w[1], w[2], w[3]);
    *(float4*)&wsm[ti][d0 + 4] = make_float4(w[4], w[5], w[6], w[7]);
#pragma unroll
    for (int u = 0; u < 8; ++u) {
      const int off = j0t + d0 + u - iglob;
      if (off <= -256) lacc += w[u];
      else if (off >= 256) hacc += w[u];
      else wrel[ti][off + 256] = f2bf(w[u]);
    }
    __syncthreads();
#pragma unroll 8
    for (int j = 0; j < 64; ++j) {
      const float wv = wsm[ti][j];
      const float4 v1 = *(const float4*)&vs[j][d0];
      const float4 v2 = *(const float4*)&vs[j][d0 + 4];
      acc[0] += wv * v1.x; acc[1] += wv * v1.y; acc[2] += wv * v1.z; acc[3] += wv * v1.w;
      acc[4] += wv * v2.x; acc[5] += wv * v2.y; acc[6] += wv * v2.z; acc[7] += wv * v2.w;
    }
    __syncthreads();
  }

  // deterministic reduction of clamped bins across the 8 threads of a row
  wsm[ti][dq] = lacc;
  wsm[ti][8 + dq] = hacc;
  __syncthreads();
  float lv = 0.f, hv = 0.f;
#pragma unroll
  for (int x = 0; x < 8; ++x) { lv += wsm[ti][x]; hv += wsm[ti][8 + x]; }
  __syncthreads();

  // rel term: acc += sum_r wrel[i][r] * Ev[r][:], r = 0..511 staged via LDS
  for (int rc = 0; rc < 512; rc += 64) {
#pragma unroll
    for (int u = 0; u < 4; ++u) {
      const int l = t + (u << 8);
      const int rr = l >> 4, dv = (l & 15) << 2;
      *(float4*)&vs[rr][dv] = *(const float4*)&Ev[(size_t)(rc + rr) * HD + dv];
    }
    __syncthreads();
#pragma unroll 8
    for (int r = 0; r < 64; ++r) {
      const float wr = bf2f(wrel[ti][rc + r]);
      const float4 v1 = *(const float4*)&vs[r][d0];
      const float4 v2 = *(const float4*)&vs[r][d0 + 4];
      acc[0] += wr * v1.x; acc[1] += wr * v1.y; acc[2] += wr * v1.z; acc[3] += wr * v1.w;
      acc[4] += wr * v2.x; acc[5] += wr * v2.y; acc[6] += wr * v2.z; acc[7] += wr * v2.w;
    }
    __syncthreads();
  }
  {  // clamped bins hit Ev rows 0 and 512 exactly
    const float4 e1 = *(const float4*)&Ev[d0];
    const float4 e2 = *(const float4*)&Ev[d0 + 4];
    const float4 e3 = *(const float4*)&Ev[512 * HD + d0];
    const float4 e4 = *(const float4*)&Ev[512 * HD + d0 + 4];
    acc[0] += lv * e1.x + hv * e3.x; acc[1] += lv * e1.y + hv * e3.y;
    acc[2] += lv * e1.z + hv * e3.z; acc[3] += lv * e1.w + hv * e3.w;
    acc[4] += lv * e2.x + hv * e4.x; acc[5] += lv * e2.y + hv * e4.y;
    acc[6] += lv * e2.z + hv * e4.z; acc[7] += lv * e2.w + hv * e4.w;
  }
  float* crow = concat + ((size_t)b * SS + iglob) * DM + h * HD + d0;
  *(float4*)&crow[0] = make_float4(acc[0], acc[1], acc[2], acc[3]);
  *(float4*)&crow[4] = make_float4(acc[4], acc[5], acc[6], acc[7]);
}

extern "C" void kernel_launch(void* const* d_in, const int* in_sizes, int n_in,
                              void* d_out, int out_size, void* d_ws, size_t ws_size,
                              hipStream_t stream) {
  (void)in_sizes; (void)n_in; (void)out_size; (void)ws_size;
  const float* query = (const float*)d_in[0];
  const float* value = (const float*)d_in[1];
  const float* Wq = (const float*)d_in[2];
  const float* Wk = (const float*)d_in[3];
  const float* Wv = (const float*)d_in[4];
  const float* Wo = (const float*)d_in[5];
  const float* bo = (const float*)d_in[6];
  const float* Ek = (const float*)d_in[7];
  const float* Ev = (const float*)d_in[8];

  float* out = (float*)d_out;                                // (B,S,512)
  float* attn = out + (size_t)SB * SS * DM;                  // (B,H,S,S)

  float* ws = (float*)d_ws;
  const size_t NPROJ = (size_t)SB * SS * DM;                 // 2M floats
  float* Qp = ws;
  float* Kp = ws + NPROJ;
  float* Vp = ws + 2 * NPROJ;
  float* concat = ws + 3 * NPROJ;
  float* m_arr = ws + 4 * NPROJ;
  float* z_arr = m_arr + (size_t)SB * HH * SS;

  const int M = SB * SS;  // 4096
  dim3 blk(256);
  dim3 ggrid((M / 64) * (DM / 64));  // 512

  gemm_f32<<<ggrid, blk, 0, stream>>>(query, Wq, nullptr, Qp, M, DM, DM);
  gemm_f32<<<ggrid, blk, 0, stream>>>(value, Wk, nullptr, Kp, M, DM, DM);
  gemm_f32<<<ggrid, blk, 0, stream>>>(value, Wv, nullptr, Vp, M, DM, DM);
  attn_logits<<<dim3(SB * HH * 128), blk, 0, stream>>>(Qp, Kp, Ek, attn, m_arr, z_arr);
  attn_pv<<<dim3(SB * HH * 64), blk, 0, stream>>>(Vp, Ev, m_arr, z_arr, attn, concat);
  gemm_f32<<<ggrid, blk, 0, stream>>>(concat, Wo, bo, out, M, DM, DM);
}

// Round 3
// 486.676 us; speedup vs baseline: 2.2320x; 2.2320x over previous
//
#include <hip/hip_runtime.h>

#define SB 2
#define HH 8
#define SS 2048
#define DM 512
#define HD 64
#define SCALE 0.125f

typedef __attribute__((ext_vector_type(8))) short bfrag;   // 8 x bf16
typedef __attribute__((ext_vector_type(4))) float f4;

static __device__ __forceinline__ unsigned short f2bf(float x) {
  unsigned int u = __float_as_uint(x);
  unsigned int r = (u + 0x7FFFu + ((u >> 16) & 1u)) >> 16;
  return (unsigned short)r;
}
static __device__ __forceinline__ float bf2f(unsigned short s) {
  return __uint_as_float(((unsigned int)s) << 16);
}
static __device__ __forceinline__ void splitf(float x, short& hi, short& lo) {
  const unsigned u = __float_as_uint(x);
  hi = (short)(u >> 16);                                    // truncation
  lo = (short)f2bf(x - __uint_as_float(u & 0xFFFF0000u));   // RTNE residual
}

// ---------------- generic fp32 GEMM: C[M][N] = A[M][K] @ B[K][N] (+bias) ---
// (proven in round 1)
__global__ __launch_bounds__(256) void gemm_f32(const float* __restrict__ A,
                                                const float* __restrict__ Bm,
                                                const float* __restrict__ bias,
                                                float* __restrict__ C,
                                                int M, int N, int K) {
  __shared__ float As[16][68];   // [k][m], padded
  __shared__ float Bs[16][64];   // [k][n]
  const int t = threadIdx.x;
  const int nb = N >> 6;
  const int bm = blockIdx.x / nb, bn = blockIdx.x % nb;
  const int m0 = bm << 6, n0 = bn << 6;
  const int ty = t >> 4, tx = t & 15;
  const int mr = ty << 2, nc = tx << 2;
  const int am = t >> 2, akq = t & 3;
  const int bk = t >> 4, bnq = t & 15;
  float acc[4][4] = {};
  for (int k0 = 0; k0 < K; k0 += 16) {
    const float4 av = *(const float4*)&A[(size_t)(m0 + am) * K + k0 + (akq << 2)];
    const float4 bv = *(const float4*)&Bm[(size_t)(k0 + bk) * N + n0 + (bnq << 2)];
    __syncthreads();
    As[(akq << 2) + 0][am] = av.x;
    As[(akq << 2) + 1][am] = av.y;
    As[(akq << 2) + 2][am] = av.z;
    As[(akq << 2) + 3][am] = av.w;
    *(float4*)&Bs[bk][bnq << 2] = bv;
    __syncthreads();
#pragma unroll
    for (int kk = 0; kk < 16; ++kk) {
      float a[4], b[4];
      *(float4*)a = *(const float4*)&As[kk][mr];
      *(float4*)b = *(const float4*)&Bs[kk][nc];
#pragma unroll
      for (int i = 0; i < 4; ++i)
#pragma unroll
        for (int j = 0; j < 4; ++j) acc[i][j] += a[i] * b[j];
    }
  }
#pragma unroll
  for (int i = 0; i < 4; ++i) {
    float4 v = make_float4(acc[i][0], acc[i][1], acc[i][2], acc[i][3]);
    if (bias) {
      v.x += bias[n0 + nc + 0];
      v.y += bias[n0 + nc + 1];
      v.z += bias[n0 + nc + 2];
      v.w += bias[n0 + nc + 3];
    }
    *(float4*)&C[(size_t)(m0 + mr + i) * N + n0 + nc] = v;
  }
}

// -------- gemm_f32_vt: same compute, epilogue writes per-head transposed ---
// VT[bh][d][j] bf16 (V projection fused with transpose; no fp32 Vp needed).
__global__ __launch_bounds__(256) void gemm_f32_vt(const float* __restrict__ A,
                                                   const float* __restrict__ Bm,
                                                   unsigned short* __restrict__ VT,
                                                   int M, int N, int K) {
  __shared__ float As[16][68];
  __shared__ float Bs[16][64];
  const int t = threadIdx.x;
  const int nb = N >> 6;
  const int bm = blockIdx.x / nb, bn = blockIdx.x % nb;
  const int m0 = bm << 6, n0 = bn << 6;
  const int ty = t >> 4, tx = t & 15;
  const int mr = ty << 2, nc = tx << 2;
  const int am = t >> 2, akq = t & 3;
  const int bk = t >> 4, bnq = t & 15;
  float acc[4][4] = {};
  for (int k0 = 0; k0 < K; k0 += 16) {
    const float4 av = *(const float4*)&A[(size_t)(m0 + am) * K + k0 + (akq << 2)];
    const float4 bv = *(const float4*)&Bm[(size_t)(k0 + bk) * N + n0 + (bnq << 2)];
    __syncthreads();
    As[(akq << 2) + 0][am] = av.x;
    As[(akq << 2) + 1][am] = av.y;
    As[(akq << 2) + 2][am] = av.z;
    As[(akq << 2) + 3][am] = av.w;
    *(float4*)&Bs[bk][bnq << 2] = bv;
    __syncthreads();
#pragma unroll
    for (int kk = 0; kk < 16; ++kk) {
      float a[4], b[4];
      *(float4*)a = *(const float4*)&As[kk][mr];
      *(float4*)b = *(const float4*)&Bs[kk][nc];
#pragma unroll
      for (int i = 0; i < 4; ++i)
#pragma unroll
        for (int j = 0; j < 4; ++j) acc[i][j] += a[i] * b[j];
    }
  }
#pragma unroll
  for (int i = 0; i < 4; ++i) {
    const int row = m0 + mr + i;             // 0..4095
    const int bb = row >> 11, jr = row & 2047;
#pragma unroll
    for (int jx = 0; jx < 4; ++jx) {
      const int col = n0 + nc + jx;
      const int bh = bb * HH + (col >> 6), d = col & 63;
      VT[((size_t)bh * HD + d) * SS + jr] = f2bf(acc[i][jx]);
    }
  }
}

// ---------------------------------------------------------------------------
// prep_k: Kp fp32 -> per-head bf16 hi/lo [bh][j][64]. grid 2048.
// ---------------------------------------------------------------------------
__global__ __launch_bounds__(256) void prep_k(const float* __restrict__ Kp,
                                              unsigned short* __restrict__ kh,
                                              unsigned short* __restrict__ kl) {
  const int idx = blockIdx.x * 256 + threadIdx.x;     // float4 index over [4096][512]
  const int g = idx << 2;
  const int row = g >> 9, col = g & 511;
  const int b = row >> 11, i = row & 2047;
  const int h = col >> 6, d = col & 63;
  const f4 v = *(const f4*)&Kp[(size_t)row * DM + col];
  const size_t o = ((size_t)((b * HH + h) * SS + i)) * HD + d;
  unsigned short hh[4], ll[4];
#pragma unroll
  for (int c = 0; c < 4; ++c) {
    short hi, lo;
    splitf(v[c], hi, lo);
    hh[c] = (unsigned short)hi; ll[c] = (unsigned short)lo;
  }
  *(uint2*)&kh[o] = make_uint2((unsigned)hh[0] | ((unsigned)hh[1] << 16),
                               (unsigned)hh[2] | ((unsigned)hh[3] << 16));
  *(uint2*)&kl[o] = make_uint2((unsigned)ll[0] | ((unsigned)ll[1] << 16),
                               (unsigned)ll[2] | ((unsigned)ll[3] << 16));
}

// ---------------------------------------------------------------------------
// prep_evt: Ev fp32 [513][64] -> EvT bf16 [64][544] (transposed, zero-padded).
// ---------------------------------------------------------------------------
__global__ void prep_evt(const float* __restrict__ Ev, unsigned short* __restrict__ EvT) {
  const int idx = blockIdx.x * 256 + threadIdx.x;
  if (idx >= 64 * 544) return;
  const int d = idx / 544, r = idx % 544;
  EvT[idx] = (r < 513) ? f2bf(Ev[(size_t)r * HD + d]) : (unsigned short)0;
}

// ---------------------------------------------------------------------------
// fused_attn2: 2-sweep flash attention with relative bias, all-in-LDS extras.
// grid 1024 (bh x 32-row block). 4 waves: rg = row half (16), jh = j half.
// Prologue: qek[32][513] into LDS via MFMA. Sweep 1: online (m,z).
// Sweep 2: w -> attn (single write), PV MFMA, banded weights into wband LDS.
// Epilogue: bins into wband cols 0/512, band GEMM wband@EvT added to concat.
// ---------------------------------------------------------------------------
__global__ __launch_bounds__(256) void fused_attn2(
    const float* __restrict__ Qp,
    const unsigned short* __restrict__ khg,
    const unsigned short* __restrict__ klg,
    const unsigned short* __restrict__ VTg,
    const float* __restrict__ Ek,
    const unsigned short* __restrict__ EvT,
    float* __restrict__ attn,
    float* __restrict__ concat) {
  __shared__ __attribute__((aligned(16))) unsigned short qek_lds[32][520];
  __shared__ __attribute__((aligned(16))) unsigned short wband[32][552];
  __shared__ __attribute__((aligned(16))) unsigned short wlds[4][16][40];
  __shared__ float mzb[2][2][16][2];
  __shared__ float lhb[2][2][16][2];

  const int t = threadIdx.x;
  const int bh = blockIdx.x >> 6, rb = blockIdx.x & 63;
  const int b = bh >> 3, h = bh & 7;
  const int wv = t >> 6, lane = t & 63;
  const int ln = lane & 15, lq = lane >> 4;
  const int rg = wv & 1, jh = wv >> 1;
  const int iw = rb * 32 + rg * 16;
  const int jbase = jh * 1024;

  // zero wband (covers never-visited band entries + MFMA pad cols)
  {
    unsigned* wz = (unsigned*)&wband[0][0];
    for (int x = t; x < 32 * 552 / 2; x += 256) wz[x] = 0;
  }

  // main Q fragments hi/lo for this wave's rows
  bfrag qh0, qh1, ql0, ql1;
  {
    const float* qrow = Qp + (size_t)(b * SS + iw + ln) * DM + h * HD + lq * 8;
    const f4 x0 = *(const f4*)&qrow[0], x1 = *(const f4*)&qrow[4];
    const f4 x2 = *(const f4*)&qrow[32], x3 = *(const f4*)&qrow[36];
#pragma unroll
    for (int e = 0; e < 4; ++e) {
      short hi, lo;
      splitf(x0[e], hi, lo); qh0[e] = hi; ql0[e] = lo;
      splitf(x1[e], hi, lo); qh0[e + 4] = hi; ql0[e + 4] = lo;
      splitf(x2[e], hi, lo); qh1[e] = hi; ql1[e] = lo;
      splitf(x3[e], hi, lo); qh1[e + 4] = hi; ql1[e + 4] = lo;
    }
  }

  // qek fill: wave handles rt = wv&1 rows, nt = (wv>>1) + 2k column tiles
  {
    const int rt = wv & 1;
    bfrag ea0, ea1;
    {
      const float* q2 = Qp + (size_t)(b * SS + rb * 32 + rt * 16 + ln) * DM + h * HD + lq * 8;
      const f4 x0 = *(const f4*)&q2[0], x1 = *(const f4*)&q2[4];
      const f4 x2 = *(const f4*)&q2[32], x3 = *(const f4*)&q2[36];
#pragma unroll
      for (int e = 0; e < 4; ++e) {
        ea0[e] = (short)f2bf(x0[e]); ea0[e + 4] = (short)f2bf(x1[e]);
        ea1[e] = (short)f2bf(x2[e]); ea1[e + 4] = (short)f2bf(x3[e]);
      }
    }
    for (int nt = (wv >> 1); nt <= 32; nt += 2) {
      const int r = nt * 16 + ln;
      const int rc = r > 512 ? 512 : r;
      const float* erow = Ek + (size_t)rc * HD + lq * 8;
      const f4 a0 = *(const f4*)&erow[0], a1 = *(const f4*)&erow[4];
      const f4 a2 = *(const f4*)&erow[32], a3 = *(const f4*)&erow[36];
      bfrag e0, e1;
#pragma unroll
      for (int e = 0; e < 4; ++e) {
        e0[e] = (short)f2bf(a0[e]); e0[e + 4] = (short)f2bf(a1[e]);
        e1[e] = (short)f2bf(a2[e]); e1[e + 4] = (short)f2bf(a3[e]);
      }
      f4 acc = {0.f, 0.f, 0.f, 0.f};
      acc = __builtin_amdgcn_mfma_f32_16x16x32_bf16(ea0, e0, acc, 0, 0, 0);
      acc = __builtin_amdgcn_mfma_f32_16x16x32_bf16(ea1, e1, acc, 0, 0, 0);
      if (r < 513) {
#pragma unroll
        for (int rr = 0; rr < 4; ++rr)
          qek_lds[rt * 16 + lq * 4 + rr][r] = f2bf(acc[rr]);
      }
    }
  }
  __syncthreads();   // #1: qek + wband-zero ready

  const unsigned short* khb = khg + (size_t)bh * SS * HD;
  const unsigned short* klb = klg + (size_t)bh * SS * HD;
  const unsigned short* vtb = VTg + (size_t)bh * HD * SS;
  const int row0 = iw + lq * 4;          // lane's first output row (global)
  const int rloc0 = rg * 16 + lq * 4;    // same, block-local

  float m[4], z[4];
#pragma unroll
  for (int r = 0; r < 4; ++r) { m[r] = -3.0e38f; z[r] = 0.f; }

  // ---- sweep 1: online (m, z)
#pragma unroll 2
  for (int j0 = jbase; j0 < jbase + 1024; j0 += 16) {
    const unsigned short* kj = khb + (size_t)(j0 + ln) * HD + lq * 8;
    const unsigned short* lj = klb + (size_t)(j0 + ln) * HD + lq * 8;
    const bfrag k0 = *(const bfrag*)kj;
    const bfrag k1 = *(const bfrag*)(kj + 32);
    const bfrag l0 = *(const bfrag*)lj;
    const bfrag l1 = *(const bfrag*)(lj + 32);
    f4 acc = {0.f, 0.f, 0.f, 0.f};
    acc = __builtin_amdgcn_mfma_f32_16x16x32_bf16(qh0, k0, acc, 0, 0, 0);
    acc = __builtin_amdgcn_mfma_f32_16x16x32_bf16(qh1, k1, acc, 0, 0, 0);
    acc = __builtin_amdgcn_mfma_f32_16x16x32_bf16(ql0, k0, acc, 0, 0, 0);
    acc = __builtin_amdgcn_mfma_f32_16x16x32_bf16(ql1, k1, acc, 0, 0, 0);
    acc = __builtin_amdgcn_mfma_f32_16x16x32_bf16(qh0, l0, acc, 0, 0, 0);
    acc = __builtin_amdgcn_mfma_f32_16x16x32_bf16(qh1, l1, acc, 0, 0, 0);
    const int j = j0 + ln;
#pragma unroll
    for (int r = 0; r < 4; ++r) {
      const int row = row0 + r;
      int off = j - row;
      off = off < -256 ? -256 : (off > 256 ? 256 : off);
      const float qv = bf2f(qek_lds[rloc0 + r][off + 256]);
      const float l = (acc[r] + qv) * SCALE;
      const float nm = fmaxf(m[r], l);
      z[r] = z[r] * __expf(m[r] - nm) + __expf(l - nm);
      m[r] = nm;
    }
  }
  // merge within 16-lane groups
#pragma unroll
  for (int r = 0; r < 4; ++r) {
#pragma unroll
    for (int o = 1; o < 16; o <<= 1) {
      const float om = __shfl_xor(m[r], o);
      const float oz = __shfl_xor(z[r], o);
      const float nm = fmaxf(m[r], om);
      z[r] = z[r] * __expf(m[r] - nm) + oz * __expf(om - nm);
      m[r] = nm;
    }
  }
  if (ln == 0) {
#pragma unroll
    for (int r = 0; r < 4; ++r) {
      mzb[rg][jh][lq * 4 + r][0] = m[r];
      mzb[rg][jh][lq * 4 + r][1] = z[r];
    }
  }
  __syncthreads();   // #2
  float zi[4];
#pragma unroll
  for (int r = 0; r < 4; ++r) {
    const float om = mzb[rg][jh ^ 1][lq * 4 + r][0];
    const float oz = mzb[rg][jh ^ 1][lq * 4 + r][1];
    const float nm = fmaxf(m[r], om);
    z[r] = z[r] * __expf(m[r] - nm) + oz * __expf(om - nm);
    m[r] = nm;
    zi[r] = 1.f / z[r];
  }

  // ---- sweep 2: write normalized w, band/bins, PV
  f4 pv[4] = {{0.f,0.f,0.f,0.f},{0.f,0.f,0.f,0.f},{0.f,0.f,0.f,0.f},{0.f,0.f,0.f,0.f}};
  float la[4] = {0.f, 0.f, 0.f, 0.f}, ha[4] = {0.f, 0.f, 0.f, 0.f};
#pragma unroll 1
  for (int jc = jbase; jc < jbase + 1024; jc += 32) {
#pragma unroll
    for (int s = 0; s < 2; ++s) {
      const int j0 = jc + s * 16;
      const unsigned short* kj = khb + (size_t)(j0 + ln) * HD + lq * 8;
      const unsigned short* lj = klb + (size_t)(j0 + ln) * HD + lq * 8;
      const bfrag k0 = *(const bfrag*)kj;
      const bfrag k1 = *(const bfrag*)(kj + 32);
      const bfrag l0 = *(const bfrag*)lj;
      const bfrag l1 = *(const bfrag*)(lj + 32);
      f4 acc = {0.f, 0.f, 0.f, 0.f};
      acc = __builtin_amdgcn_mfma_f32_16x16x32_bf16(qh0, k0, acc, 0, 0, 0);
      acc = __builtin_amdgcn_mfma_f32_16x16x32_bf16(qh1, k1, acc, 0, 0, 0);
      acc = __builtin_amdgcn_mfma_f32_16x16x32_bf16(ql0, k0, acc, 0, 0, 0);
      acc = __builtin_amdgcn_mfma_f32_16x16x32_bf16(ql1, k1, acc, 0, 0, 0);
      acc = __builtin_amdgcn_mfma_f32_16x16x32_bf16(qh0, l0, acc, 0, 0, 0);
      acc = __builtin_amdgcn_mfma_f32_16x16x32_bf16(qh1, l1, acc, 0, 0, 0);
      const int j = j0 + ln;
#pragma unroll
      for (int r = 0; r < 4; ++r) {
        const int row = row0 + r;
        const int off = j - row;
        const int offc = off < -256 ? -256 : (off > 256 ? 256 : off);
        const float qv = bf2f(qek_lds[rloc0 + r][offc + 256]);
        const float l = (acc[r] + qv) * SCALE;
        const float w = __expf(l - m[r]) * zi[r];
        attn[((size_t)bh * SS + row) * SS + j] = w;
        const unsigned short wb = f2bf(w);
        if (off <= -256) la[r] += w;
        else if (off >= 256) ha[r] += w;
        else wband[rloc0 + r][off + 256] = wb;
        wlds[wv][lq * 4 + r][s * 16 + ln] = wb;
      }
    }
    const bfrag pa = *(const bfrag*)&wlds[wv][ln][lq * 8];
#pragma unroll
    for (int dt = 0; dt < 4; ++dt) {
      const bfrag pb = *(const bfrag*)&vtb[(size_t)(dt * 16 + ln) * SS + jc + lq * 8];
      pv[dt] = __builtin_amdgcn_mfma_f32_16x16x32_bf16(pa, pb, pv[dt], 0, 0, 0);
    }
  }
  // merge boundary bins across 16-lane groups
#pragma unroll
  for (int r = 0; r < 4; ++r) {
#pragma unroll
    for (int o = 1; o < 16; o <<= 1) {
      la[r] += __shfl_xor(la[r], o);
      ha[r] += __shfl_xor(ha[r], o);
    }
  }
  if (ln == 0) {
#pragma unroll
    for (int r = 0; r < 4; ++r) {
      lhb[rg][jh][lq * 4 + r][0] = la[r];
      lhb[rg][jh][lq * 4 + r][1] = ha[r];
    }
  }
  __syncthreads();   // #3: wband interior + lhb complete

  // bins -> wband cols 0 / 512 (fold into the band GEMM)
  if (t < 32) {
    const int rg2 = t >> 4, r16 = t & 15;
    wband[t][0]   = f2bf(lhb[rg2][0][r16][0] + lhb[rg2][1][r16][0]);
    wband[t][512] = f2bf(lhb[rg2][0][r16][1] + lhb[rg2][1][r16][1]);
  }
  // phase A: jh0 waves write their PV partial to concat
  if (jh == 0) {
#pragma unroll
    for (int dt = 0; dt < 4; ++dt)
#pragma unroll
      for (int r = 0; r < 4; ++r)
        concat[(size_t)(b * SS + row0 + r) * DM + h * HD + dt * 16 + ln] = pv[dt][r];
  }
  __syncthreads();   // #4: bins visible in LDS, phase-A stores visible in block

  // phase B: jh1 waves add band GEMM (wband @ EvT) into their PV, then RMW
  if (jh == 1) {
    for (int kt = 0; kt < 17; ++kt) {
      const bfrag a = *(const bfrag*)&wband[rg * 16 + ln][kt * 32 + lq * 8];
#pragma unroll
      for (int dt = 0; dt < 4; ++dt) {
        const bfrag bb = *(const bfrag*)&EvT[(size_t)(dt * 16 + ln) * 544 + kt * 32 + lq * 8];
        pv[dt] = __builtin_amdgcn_mfma_f32_16x16x32_bf16(a, bb, pv[dt], 0, 0, 0);
      }
    }
#pragma unroll
    for (int dt = 0; dt < 4; ++dt)
#pragma unroll
      for (int r = 0; r < 4; ++r) {
        float* p = &concat[(size_t)(b * SS + row0 + r) * DM + h * HD + dt * 16 + ln];
        *p += pv[dt][r];
      }
  }
}

// ---------------------------------------------------------------------------
extern "C" void kernel_launch(void* const* d_in, const int* in_sizes, int n_in,
                              void* d_out, int out_size, void* d_ws, size_t ws_size,
                              hipStream_t stream) {
  (void)in_sizes; (void)n_in; (void)out_size; (void)ws_size;
  const float* query = (const float*)d_in[0];
  const float* value = (const float*)d_in[1];
  const float* Wq = (const float*)d_in[2];
  const float* Wk = (const float*)d_in[3];
  const float* Wv = (const float*)d_in[4];
  const float* Wo = (const float*)d_in[5];
  const float* bo = (const float*)d_in[6];
  const float* Ek = (const float*)d_in[7];
  const float* Ev = (const float*)d_in[8];

  float* out = (float*)d_out;
  float* attn = out + (size_t)SB * SS * DM;

  // workspace carve — 29.43 MB total (round-1 proved >=33.8 MB is safe)
  char* wsb = (char*)d_ws;
  float* Qp = (float*)(wsb + 0);                             //  8 MB
  float* Kp = (float*)(wsb + 8388608);                       //  8 MB (→ concat)
  float* concat = Kp;                                        //  alias: Kp dead after prep_k
  unsigned short* kb16h = (unsigned short*)(wsb + 16777216); //  4 MB
  unsigned short* kb16l = (unsigned short*)(wsb + 20971520); //  4 MB
  unsigned short* VT = (unsigned short*)(wsb + 25165824);    //  4 MB
  unsigned short* EvT = (unsigned short*)(wsb + 29360128);   //  68 KB

  const int M = SB * SS;  // 4096
  dim3 blk(256);
  dim3 ggrid((M / 64) * (DM / 64));  // 512

  gemm_f32<<<ggrid, blk, 0, stream>>>(query, Wq, nullptr, Qp, M, DM, DM);
  gemm_f32<<<ggrid, blk, 0, stream>>>(value, Wk, nullptr, Kp, M, DM, DM);
  gemm_f32_vt<<<ggrid, blk, 0, stream>>>(value, Wv, VT, M, DM, DM);
  prep_k<<<2048, blk, 0, stream>>>(Kp, kb16h, kb16l);
  prep_evt<<<136, blk, 0, stream>>>(Ev, EvT);
  fused_attn2<<<1024, blk, 0, stream>>>(Qp, kb16h, kb16l, VT, Ek, EvT, attn, concat);
  gemm_f32<<<ggrid, blk, 0, stream>>>(concat, Wo, bo, out, M, DM, DM);
}